// Round 8
// baseline (445.336 us; speedup 1.0000x reference)
//
#include <hip/hip_runtime.h>
#include <hip/hip_bf16.h>
#include <cstdint>

// ---------------------------------------------------------------------------
// Gemma4 MoE FFN. N=4096 tokens, H=1024, ID=4096, IM=512, E=8, top-2.
// Round 8: fused up-GEMMs (two K-passes, gelu(G) packed bf16 in regs, no
// G round-trip through HBM), sigmoid-form gelu, dense-down 2-phase dbuf.
// Router/moe bookkeeping (zero global atomics) and expert-down unchanged.
// ---------------------------------------------------------------------------

typedef __attribute__((ext_vector_type(8))) short short8;
typedef __attribute__((ext_vector_type(4))) float floatx4;
typedef const void __attribute__((address_space(1)))* gptr_t;
typedef void __attribute__((address_space(3)))* sptr_t;

#define BF16 __hip_bfloat16

// gelu-tanh via sigmoid identity: 0.5x(1+tanh(c(x+0.044715x^3))) =
// x * sigma(2c*x + 2c*0.044715*x^3), 2c = 1.5957691216
__device__ __forceinline__ float gelu_sig(float x) {
  float z = x * (1.5957691216f + 0.07135481283f * x * x);
  return x / (1.f + __expf(-z));
}

__device__ __forceinline__ unsigned bf16bits(float f) {
  union { BF16 b; unsigned short u; } c;
  c.b = __float2bfloat16(f);
  return c.u;
}
__device__ __forceinline__ float bits2f(unsigned bf) {
  union { unsigned u; float f; } c;
  c.u = bf << 16;
  return c.f;
}

// ---------------------------------------------------------------------------
// [128][64] bf16 tile staging, granule-XOR swizzle (measured: conflicts -> 0).
// LDS slot g holds source granule g ^ (row&7).
// ---------------------------------------------------------------------------
__device__ __forceinline__ void stage128x64(const BF16* __restrict__ g, BF16* lds,
                                            int ldg, int wave, int lane) {
  const int rsub = lane >> 3;
  const int gcol = lane & 7;
#pragma unroll
  for (int j = 0; j < 4; ++j) {
    int row = wave * 32 + j * 8 + rsub;
    const BF16* src = g + (size_t)row * ldg + ((gcol ^ rsub) * 8);
    BF16* dst = lds + (wave * 32 + j * 8) * 64;  // wave-uniform; HW adds lane*16B
    __builtin_amdgcn_global_load_lds((gptr_t)src, (sptr_t)dst, 16, 0, 0);
  }
}

__device__ __forceinline__ void stage128x64_indir(const BF16* __restrict__ xr,
                                                  const int* __restrict__ tok,
                                                  int kofs, BF16* lds, int wave, int lane) {
  const int rsub = lane >> 3;
  const int gcol = lane & 7;
#pragma unroll
  for (int j = 0; j < 4; ++j) {
    const BF16* src = xr + (size_t)tok[j] * 1024 + kofs + ((gcol ^ rsub) * 8);
    BF16* dst = lds + (wave * 32 + j * 8) * 64;
    __builtin_amdgcn_global_load_lds((gptr_t)src, (sptr_t)dst, 16, 0, 0);
  }
}

__device__ __forceinline__ short8 frag64(const BF16* lds, int fr, int kh, int lane) {
  int gk = kh * 4 + (lane >> 4);
  return *(const short8*)&lds[fr * 64 + ((gk ^ (fr & 7)) * 8)];
}

// BK=32 variants (round-5-verified): slot g holds source granule g^((row>>1)&3)
__device__ __forceinline__ void stage32(const BF16* __restrict__ g, BF16* lds,
                                        int ldg, int wave, int lane) {
  const int g4 = (lane & 3) ^ ((lane >> 3) & 3);
#pragma unroll
  for (int j = 0; j < 2; ++j) {
    int row = wave * 32 + j * 16 + (lane >> 2);
    const BF16* src = g + (size_t)row * ldg + g4 * 8;
    BF16* dst = lds + (wave * 32 + j * 16) * 32;
    __builtin_amdgcn_global_load_lds((gptr_t)src, (sptr_t)dst, 16, 0, 0);
  }
}
__device__ __forceinline__ short8 frag32(const BF16* lds, int fr, int lane) {
  int gk = lane >> 4;
  return *(const short8*)&lds[fr * 32 + ((gk ^ ((fr >> 1) & 3)) * 8)];
}

// ---------------------------------------------------------------------------
// Fused dual up-GEMM, two sequential K-passes sharing LDS:
//   pass1: Gacc = A@Bg ; pg = bf16(gelu(Gacc)) packed in 32 VGPR
//   pass2: Uacc = A@Bu ; out = pg * Uacc (* row_w)
// GROUPED: desc/eB/row_w/ldo=512; INDIR: A rows via row_token.
// ---------------------------------------------------------------------------
template <int INDIR, int GROUPED>
__launch_bounds__(256, 3)
__global__ void gemm_up_fused(const BF16* __restrict__ A, int lda,
                              const BF16* __restrict__ Bg, const BF16* __restrict__ Bu,
                              int ldb, int eB,
                              const int2* __restrict__ desc,
                              const int* __restrict__ row_token,
                              const float* __restrict__ row_w,
                              BF16* __restrict__ out, int ldo, int nkt) {
  __shared__ __align__(16) BF16 la[128 * 64];
  __shared__ __align__(16) BF16 lb[128 * 64];
  int e = 0, r0;
  const int c0 = blockIdx.x * 128;
  if (GROUPED) {
    int2 d = desc[blockIdx.y];
    if (d.x < 0) return;
    e = d.x;
    r0 = d.y;
  } else {
    r0 = blockIdx.y * 128;
  }
  const int lane = threadIdx.x & 63, wave = threadIdx.x >> 6;
  const int wr = wave >> 1, wc = wave & 1;
  const BF16* Ar = A + (size_t)r0 * lda;
  const BF16* Bgr = Bg + (size_t)(GROUPED ? e * eB + c0 : c0) * ldb;
  const BF16* Bur = Bu + (size_t)(GROUPED ? e * eB + c0 : c0) * ldb;

  int tok[4];
  if (INDIR) {
#pragma unroll
    for (int j = 0; j < 4; ++j) {
      int t = row_token[r0 + wave * 32 + j * 8 + (lane >> 3)];
      tok[j] = t < 0 ? 0 : t;
    }
  }

  // ---- pass 1: G ----
  unsigned pg[4][4][2];
  {
    floatx4 accg[4][4] = {};
    for (int kt = 0; kt < nkt; ++kt) {
      if (INDIR)
        stage128x64_indir(A, tok, kt * 64, la, wave, lane);
      else
        stage128x64(Ar + kt * 64, la, lda, wave, lane);
      stage128x64(Bgr + kt * 64, lb, ldb, wave, lane);
      __syncthreads();
#pragma unroll
      for (int kh = 0; kh < 2; ++kh) {
        short8 af[4], bf[4];
#pragma unroll
        for (int mi = 0; mi < 4; ++mi)
          af[mi] = frag64(la, wr * 64 + mi * 16 + (lane & 15), kh, lane);
#pragma unroll
        for (int ni = 0; ni < 4; ++ni)
          bf[ni] = frag64(lb, wc * 64 + ni * 16 + (lane & 15), kh, lane);
#pragma unroll
        for (int mi = 0; mi < 4; ++mi)
#pragma unroll
          for (int ni = 0; ni < 4; ++ni)
            accg[mi][ni] = __builtin_amdgcn_mfma_f32_16x16x32_bf16(af[mi], bf[ni], accg[mi][ni], 0, 0, 0);
      }
      __syncthreads();
    }
#pragma unroll
    for (int mi = 0; mi < 4; ++mi)
#pragma unroll
      for (int ni = 0; ni < 4; ++ni) {
        pg[mi][ni][0] = bf16bits(gelu_sig(accg[mi][ni][0])) |
                        (bf16bits(gelu_sig(accg[mi][ni][1])) << 16);
        pg[mi][ni][1] = bf16bits(gelu_sig(accg[mi][ni][2])) |
                        (bf16bits(gelu_sig(accg[mi][ni][3])) << 16);
      }
  }

  // ---- pass 2: U ----
  floatx4 accu[4][4] = {};
  for (int kt = 0; kt < nkt; ++kt) {
    if (INDIR)
      stage128x64_indir(A, tok, kt * 64, la, wave, lane);
    else
      stage128x64(Ar + kt * 64, la, lda, wave, lane);
    stage128x64(Bur + kt * 64, lb, ldb, wave, lane);
    __syncthreads();
#pragma unroll
    for (int kh = 0; kh < 2; ++kh) {
      short8 af[4], bf[4];
#pragma unroll
      for (int mi = 0; mi < 4; ++mi)
        af[mi] = frag64(la, wr * 64 + mi * 16 + (lane & 15), kh, lane);
#pragma unroll
      for (int ni = 0; ni < 4; ++ni)
        bf[ni] = frag64(lb, wc * 64 + ni * 16 + (lane & 15), kh, lane);
#pragma unroll
      for (int mi = 0; mi < 4; ++mi)
#pragma unroll
        for (int ni = 0; ni < 4; ++ni)
          accu[mi][ni] = __builtin_amdgcn_mfma_f32_16x16x32_bf16(af[mi], bf[ni], accu[mi][ni], 0, 0, 0);
    }
    __syncthreads();
  }

  // ---- epilogue: H = gelu(G)*U (*row_w) ----
  float rw[4][4];
  if (GROUPED) {
#pragma unroll
    for (int mi = 0; mi < 4; ++mi)
#pragma unroll
      for (int j = 0; j < 4; ++j)
        rw[mi][j] = row_w[r0 + wr * 64 + mi * 16 + (lane >> 4) * 4 + j];
  }
#pragma unroll
  for (int mi = 0; mi < 4; ++mi)
#pragma unroll
    for (int ni = 0; ni < 4; ++ni)
#pragma unroll
      for (int j = 0; j < 4; ++j) {
        int r = r0 + wr * 64 + mi * 16 + (lane >> 4) * 4 + j;
        int c = c0 + wc * 64 + ni * 16 + (lane & 15);
        float g = bits2f((pg[mi][ni][j >> 1] >> ((j & 1) * 16)) & 0xffffu);
        float v = g * accu[mi][ni][j];
        if (GROUPED) v *= rw[mi][j];
        out[(size_t)r * ldo + c] = __float2bfloat16(v);
      }
}

// ---------------------------------------------------------------------------
// Plain GEMM (expert down): single-buffer BK=64, as round 7.
// ---------------------------------------------------------------------------
__launch_bounds__(256, 3)
__global__ void gemm_bt_grp(const BF16* __restrict__ A, int lda,
                            const BF16* __restrict__ B, int ldb, int eB,
                            const int2* __restrict__ desc,
                            BF16* __restrict__ out, int ldo, int nkt) {
  __shared__ __align__(16) BF16 la[128 * 64];
  __shared__ __align__(16) BF16 lb[128 * 64];
  int2 d = desc[blockIdx.y];
  if (d.x < 0) return;
  const int e = d.x, r0 = d.y;
  const int c0 = blockIdx.x * 128;
  const int lane = threadIdx.x & 63, wave = threadIdx.x >> 6;
  const int wr = wave >> 1, wc = wave & 1;
  const BF16* Ar = A + (size_t)r0 * lda;
  const BF16* Br = B + (size_t)(e * eB + c0) * ldb;

  floatx4 acc[4][4] = {};
  for (int kt = 0; kt < nkt; ++kt) {
    stage128x64(Ar + kt * 64, la, lda, wave, lane);
    stage128x64(Br + kt * 64, lb, ldb, wave, lane);
    __syncthreads();
#pragma unroll
    for (int kh = 0; kh < 2; ++kh) {
      short8 af[4], bf[4];
#pragma unroll
      for (int mi = 0; mi < 4; ++mi)
        af[mi] = frag64(la, wr * 64 + mi * 16 + (lane & 15), kh, lane);
#pragma unroll
      for (int ni = 0; ni < 4; ++ni)
        bf[ni] = frag64(lb, wc * 64 + ni * 16 + (lane & 15), kh, lane);
#pragma unroll
      for (int mi = 0; mi < 4; ++mi)
#pragma unroll
        for (int ni = 0; ni < 4; ++ni)
          acc[mi][ni] = __builtin_amdgcn_mfma_f32_16x16x32_bf16(af[mi], bf[ni], acc[mi][ni], 0, 0, 0);
    }
    __syncthreads();
  }
#pragma unroll
  for (int mi = 0; mi < 4; ++mi)
#pragma unroll
    for (int ni = 0; ni < 4; ++ni)
#pragma unroll
      for (int j = 0; j < 4; ++j) {
        int r = r0 + wr * 64 + mi * 16 + (lane >> 4) * 4 + j;
        int c = c0 + wc * 64 + ni * 16 + (lane & 15);
        out[(size_t)r * ldo + c] = __float2bfloat16(acc[mi][ni][j]);
      }
}

// ---------------------------------------------------------------------------
// Dense down: 2-phase dbuf BK=32, split-K=2 via z, bf16 partials.
// A=HBUF[4096][4096], B=WddT[1024][4096].
// ---------------------------------------------------------------------------
__launch_bounds__(256, 3)
__global__ void gemm_down_2ph(const BF16* __restrict__ A, const BF16* __restrict__ B,
                              BF16* __restrict__ outp) {
  __shared__ __align__(16) BF16 la[2][128 * 32];
  __shared__ __align__(16) BF16 lb[2][128 * 32];
  const int r0 = blockIdx.y * 128, c0 = blockIdx.x * 128;
  const int lane = threadIdx.x & 63, wave = threadIdx.x >> 6;
  const int wr = wave >> 1, wc = wave & 1;
  constexpr int NT = 64;  // 2048 / 32
  const BF16* Ar = A + (size_t)r0 * 4096 + blockIdx.z * 2048;
  const BF16* Br = B + (size_t)c0 * 4096 + blockIdx.z * 2048;
  outp += (size_t)blockIdx.z * 4096 * 1024;

  stage32(Ar, la[0], 4096, wave, lane);
  stage32(Br, lb[0], 4096, wave, lane);
  __syncthreads();

  floatx4 acc[4][4] = {};
  for (int kt = 0; kt < NT; ++kt) {
    const int cur = kt & 1;
    if (kt + 1 < NT) {  // prefetch next K-tile; drains at loop barrier
      stage32(Ar + (kt + 1) * 32, la[cur ^ 1], 4096, wave, lane);
      stage32(Br + (kt + 1) * 32, lb[cur ^ 1], 4096, wave, lane);
    }
    short8 af[4], bf[4];
#pragma unroll
    for (int mi = 0; mi < 4; ++mi)
      af[mi] = frag32(la[cur], wr * 64 + mi * 16 + (lane & 15), lane);
#pragma unroll
    for (int ni = 0; ni < 4; ++ni)
      bf[ni] = frag32(lb[cur], wc * 64 + ni * 16 + (lane & 15), lane);
#pragma unroll
    for (int mi = 0; mi < 4; ++mi)
#pragma unroll
      for (int ni = 0; ni < 4; ++ni)
        acc[mi][ni] = __builtin_amdgcn_mfma_f32_16x16x32_bf16(af[mi], bf[ni], acc[mi][ni], 0, 0, 0);
    __syncthreads();
  }
#pragma unroll
  for (int mi = 0; mi < 4; ++mi)
#pragma unroll
    for (int ni = 0; ni < 4; ++ni)
#pragma unroll
      for (int j = 0; j < 4; ++j) {
        int r = r0 + wr * 64 + mi * 16 + (lane >> 4) * 4 + j;
        int c = c0 + wc * 64 + ni * 16 + (lane & 15);
        outp[(size_t)r * 1024 + c] = __float2bfloat16(acc[mi][ni][j]);
      }
}

// ---------------------------------------------------------------------------
// Router: rmsnorm stats, xr (w_pre2, bf16), logits, softmax, top-2.
// ---------------------------------------------------------------------------
__global__ void router_kernel(const float* __restrict__ residual,
                              const float* __restrict__ w_pre2,
                              const float* __restrict__ router_scale,
                              const float* __restrict__ per_expert_scale,
                              const float* __restrict__ Wr,
                              BF16* __restrict__ xr,
                              int* __restrict__ top_i, float* __restrict__ top_w) {
  const int lane = threadIdx.x & 63, wave = threadIdx.x >> 6;
  const int n = blockIdx.x * 4 + wave;
  const float* res = residual + (size_t)n * 1024;

  float v[16];
  float ss = 0.f;
#pragma unroll
  for (int i = 0; i < 16; ++i) {
    v[i] = res[lane + i * 64];
    ss += v[i] * v[i];
  }
#pragma unroll
  for (int off = 32; off; off >>= 1) ss += __shfl_xor(ss, off);
  const float inv = rsqrtf(ss * (1.f / 1024.f) + 1e-6f);

  float logits[8] = {};
#pragma unroll
  for (int i = 0; i < 16; ++i) {
    int h = lane + i * 64;
    float nv = v[i] * inv;
    xr[(size_t)n * 1024 + h] = __float2bfloat16(nv * w_pre2[h]);
    float yv = nv * router_scale[h];
#pragma unroll
    for (int ex = 0; ex < 8; ++ex) logits[ex] += yv * Wr[h * 8 + ex];
  }
#pragma unroll
  for (int ex = 0; ex < 8; ++ex)
#pragma unroll
    for (int off = 32; off; off >>= 1) logits[ex] += __shfl_xor(logits[ex], off);

  if (lane == 0) {
    const float hscale = 0.03125f;
    float mx = -1e30f;
#pragma unroll
    for (int ex = 0; ex < 8; ++ex) {
      logits[ex] *= hscale;
      mx = fmaxf(mx, logits[ex]);
    }
    float p[8];
#pragma unroll
    for (int ex = 0; ex < 8; ++ex) p[ex] = __expf(logits[ex] - mx);
    int i0 = 0;
#pragma unroll
    for (int ex = 1; ex < 8; ++ex)
      if (p[ex] > p[i0]) i0 = ex;
    int i1 = -1;
#pragma unroll
    for (int ex = 0; ex < 8; ++ex)
      if (ex != i0 && (i1 < 0 || p[ex] > p[i1])) i1 = ex;
    float w0 = p[i0], w1 = p[i1];
    float swv = w0 + w1;
    w0 = w0 / swv * per_expert_scale[i0];
    w1 = w1 / swv * per_expert_scale[i1];
    top_i[n * 2] = i0;
    top_i[n * 2 + 1] = i1;
    top_w[n * 2] = w0;
    top_w[n * 2 + 1] = w1;
  }
}

__global__ void moe_hist(const int* __restrict__ top_i, int* __restrict__ block_hist) {
  __shared__ int h[8];
  if (threadIdx.x < 8) h[threadIdx.x] = 0;
  __syncthreads();
  atomicAdd(&h[top_i[blockIdx.x * 256 + threadIdx.x]], 1);  // LDS atomic
  __syncthreads();
  if (threadIdx.x < 8) block_hist[blockIdx.x * 8 + threadIdx.x] = h[threadIdx.x];
}

__global__ void moe_scan(const int* __restrict__ block_hist, int* __restrict__ offsets,
                         int2* __restrict__ desc, int* __restrict__ block_base,
                         int* __restrict__ row_token, float* __restrict__ row_w) {
  if (threadIdx.x == 0) {
    int acc = 0, t = 0;
    for (int e = 0; e < 8; ++e) {
      int cnt = 0;
      for (int b = 0; b < 32; ++b) cnt += block_hist[b * 8 + e];
      offsets[e] = acc;
      int run = acc;
      for (int b = 0; b < 32; ++b) {
        block_base[b * 8 + e] = run;
        run += block_hist[b * 8 + e];
      }
      int ntile = (cnt + 127) >> 7;
      for (int k = 0; k < ntile; ++k) desc[t++] = make_int2(e, acc + k * 128);
      acc += ntile * 128;
    }
    for (; t < 72; ++t) desc[t] = make_int2(-1, 0);
  }
  for (int i = threadIdx.x; i < 9216; i += blockDim.x) {
    row_token[i] = -1;
    row_w[i] = 0.f;
  }
}

__global__ void moe_assign(const int* __restrict__ top_i, const float* __restrict__ top_w,
                           const int* __restrict__ block_base,
                           int* __restrict__ row_token, float* __restrict__ row_w,
                           int* __restrict__ pair_pos) {
  __shared__ int cur[8];
  if (threadIdx.x < 8) cur[threadIdx.x] = 0;
  __syncthreads();
  const int p = blockIdx.x * 256 + threadIdx.x;
  const int e = top_i[p];
  const int rank = atomicAdd(&cur[e], 1);  // LDS atomic
  const int pos = block_base[blockIdx.x * 8 + e] + rank;
  row_token[pos] = p >> 1;
  row_w[pos] = top_w[p];
  pair_pos[p] = pos;
}

// ---------------------------------------------------------------------------
__global__ void finalize_kernel(const BF16* __restrict__ dp0, const BF16* __restrict__ dp1,
                                const BF16* __restrict__ de,
                                const int* __restrict__ pair_pos,
                                const float* __restrict__ w1, const float* __restrict__ w2,
                                float* __restrict__ out) {
  const int n = blockIdx.x, t = threadIdx.x;
  const int p0 = pair_pos[n * 2], p1 = pair_pos[n * 2 + 1];
  float d[4], r[4];
  float ssd = 0.f, ssr = 0.f;
#pragma unroll
  for (int i = 0; i < 4; ++i) {
    int h = t + i * 256;
    d[i] = __bfloat162float(dp0[(size_t)n * 1024 + h]) +
           __bfloat162float(dp1[(size_t)n * 1024 + h]);
    r[i] = __bfloat162float(de[(size_t)p0 * 1024 + h]) +
           __bfloat162float(de[(size_t)p1 * 1024 + h]);
    ssd += d[i] * d[i];
    ssr += r[i] * r[i];
  }
#pragma unroll
  for (int off = 32; off; off >>= 1) {
    ssd += __shfl_xor(ssd, off);
    ssr += __shfl_xor(ssr, off);
  }
  __shared__ float sd[4], sr[4];
  int wave = t >> 6, lane = t & 63;
  if (lane == 0) {
    sd[wave] = ssd;
    sr[wave] = ssr;
  }
  __syncthreads();
  ssd = sd[0] + sd[1] + sd[2] + sd[3];
  ssr = sr[0] + sr[1] + sr[2] + sr[3];
  const float invd = rsqrtf(ssd * (1.f / 1024.f) + 1e-6f);
  const float invr = rsqrtf(ssr * (1.f / 1024.f) + 1e-6f);
#pragma unroll
  for (int i = 0; i < 4; ++i) {
    int h = t + i * 256;
    out[(size_t)n * 1024 + h] = d[i] * invd * w1[h] + r[i] * invr * w2[h];
  }
}

// ---------------------------------------------------------------------------
__global__ void transpose_cvt(const float* __restrict__ in, BF16* __restrict__ out,
                              int rows, int cols) {
  __shared__ float tile[32][33];
  const size_t boff = (size_t)blockIdx.z * rows * cols;
  in += boff;
  out += boff;
  const int c0 = blockIdx.x * 32, r0 = blockIdx.y * 32;
#pragma unroll
  for (int i = 0; i < 4; ++i)
    tile[threadIdx.y + i * 8][threadIdx.x] =
        in[(size_t)(r0 + threadIdx.y + i * 8) * cols + c0 + threadIdx.x];
  __syncthreads();
#pragma unroll
  for (int i = 0; i < 4; ++i)
    out[(size_t)(c0 + threadIdx.y + i * 8) * rows + r0 + threadIdx.x] =
        __float2bfloat16(tile[threadIdx.x][threadIdx.y + i * 8]);
}

__global__ void cvt_bf16_kernel(const float* __restrict__ in, BF16* __restrict__ out) {
  const size_t i = ((size_t)blockIdx.x * blockDim.x + threadIdx.x) * 4;
  float4 v = *(const float4*)(in + i);
  BF16 o[4] = {__float2bfloat16(v.x), __float2bfloat16(v.y),
               __float2bfloat16(v.z), __float2bfloat16(v.w)};
  *(uint2*)(out + i) = *(const uint2*)o;
}

// ---------------------------------------------------------------------------
// Workspace (MiB offsets; lifetime-checked aliasing):
//   0.. 8  x_b     [prepass -> dense-up];  0..18.9 down_e [expert-down -> fin]
//   8..16  xr_b    [router -> expert-up]
//  16..24  WgdT    [prepass -> dense-up]
//  24..32  WudT    [prepass -> dense-up]
//  32..40  WddT    [prepass -> dense-down]
//  40..48  WgeT    [prepass -> expert-up]; 40..56 dp01 [dense-down -> fin]
//  48..56  WueT    [prepass -> expert-up]
//  56..64  WdeT_e  [prepass -> expert-down]
//  64..96  HBUF    [dense-up -> dense-down]
//  96..106 HBUF_e  [expert-up -> expert-down]
// 116..116.2 S bookkeeping [router -> finalize]
// Order: prepass, dense-up(fused), router, hist, scan, assign,
//        expert-up(fused), expert-down, dense-down(2ph split2), finalize.
// ---------------------------------------------------------------------------
extern "C" void kernel_launch(void* const* d_in, const int* in_sizes, int n_in,
                              void* d_out, int out_size, void* d_ws, size_t ws_size,
                              hipStream_t stream) {
  const float* x = (const float*)d_in[0];
  const float* res = (const float*)d_in[1];
  const float* Wg_d = (const float*)d_in[2];
  const float* Wu_d = (const float*)d_in[3];
  const float* Wd_d = (const float*)d_in[4];
  const float* w_post1 = (const float*)d_in[5];
  const float* w_pre2 = (const float*)d_in[6];
  const float* w_post2 = (const float*)d_in[7];
  const float* router_scale = (const float*)d_in[8];
  const float* per_expert_scale = (const float*)d_in[9];
  const float* Wr = (const float*)d_in[10];
  const float* Wg_e = (const float*)d_in[11];
  const float* Wu_e = (const float*)d_in[12];
  const float* Wd_e = (const float*)d_in[13];
  float* out = (float*)d_out;

  char* ws = (char*)d_ws;
  const size_t MB = 1ull << 20;
  BF16* x_b = (BF16*)(ws + 0 * MB);
  BF16* down_e = (BF16*)(ws + 0 * MB);
  BF16* xr_b = (BF16*)(ws + 8 * MB);
  BF16* WgdT = (BF16*)(ws + 16 * MB);
  BF16* WudT = (BF16*)(ws + 24 * MB);
  BF16* WddT = (BF16*)(ws + 32 * MB);
  BF16* WgeT = (BF16*)(ws + 40 * MB);
  BF16* dp01 = (BF16*)(ws + 40 * MB);
  BF16* WueT = (BF16*)(ws + 48 * MB);
  BF16* WdeT_e = (BF16*)(ws + 56 * MB);
  BF16* HBUF = (BF16*)(ws + 64 * MB);
  BF16* HBUF_e = (BF16*)(ws + 96 * MB);
  char* S = ws + 116 * MB;
  int* top_i = (int*)(S);                    // [8192]
  float* top_w = (float*)(S + 32 * 1024);    // [8192]
  int* pair_pos = (int*)(S + 64 * 1024);     // [8192]
  int* row_token = (int*)(S + 96 * 1024);    // [9216]
  float* row_w = (float*)(S + 136 * 1024);   // [9216]
  int* offsets = (int*)(S + 176 * 1024);     // [8]
  int2* desc = (int2*)(S + 177 * 1024);      // [72]
  int* block_hist = (int*)(S + 180 * 1024);  // [32][8]
  int* block_base = (int*)(S + 184 * 1024);  // [32][8]

  dim3 tb(32, 8);
  // pre-pass: conversions + weight transposes (B^T layout, bf16)
  cvt_bf16_kernel<<<4096, 256, 0, stream>>>(x, x_b);
  transpose_cvt<<<dim3(128, 32, 1), tb, 0, stream>>>(Wg_d, WgdT, 1024, 4096);
  transpose_cvt<<<dim3(128, 32, 1), tb, 0, stream>>>(Wu_d, WudT, 1024, 4096);
  transpose_cvt<<<dim3(32, 128, 1), tb, 0, stream>>>(Wd_d, WddT, 4096, 1024);
  transpose_cvt<<<dim3(16, 32, 8), tb, 0, stream>>>(Wg_e, WgeT, 1024, 512);
  transpose_cvt<<<dim3(16, 32, 8), tb, 0, stream>>>(Wu_e, WueT, 1024, 512);
  transpose_cvt<<<dim3(32, 16, 8), tb, 0, stream>>>(Wd_e, WdeT_e, 512, 1024);

  // dense up (fused): HBUF = gelu(x@Wg) * (x@Wu)
  gemm_up_fused<0, 0><<<dim3(32, 32), 256, 0, stream>>>(
      x_b, 1024, WgdT, WudT, 1024, 0, nullptr, nullptr, nullptr, HBUF, 4096, 16);

  // router + MoE bookkeeping (zero global atomics)
  router_kernel<<<1024, 256, 0, stream>>>(res, w_pre2, router_scale, per_expert_scale,
                                          Wr, xr_b, top_i, top_w);
  moe_hist<<<32, 256, 0, stream>>>(top_i, block_hist);
  moe_scan<<<1, 256, 0, stream>>>(block_hist, offsets, desc, block_base, row_token,
                                  row_w);
  moe_assign<<<32, 256, 0, stream>>>(top_i, top_w, block_base, row_token, row_w,
                                     pair_pos);

  // expert up (fused): HBUF_e = gelu(xr@Wg_e)*(xr@Wu_e)*row_w ; expert down
  gemm_up_fused<1, 1><<<dim3(4, 72), 256, 0, stream>>>(
      xr_b, 1024, WgeT, WueT, 1024, 512, desc, row_token, row_w, HBUF_e, 512, 16);
  gemm_bt_grp<<<dim3(8, 72), 256, 0, stream>>>(HBUF_e, 512, WdeT_e, 512, 1024, desc,
                                               down_e, 1024, 8);

  // dense down: 2-phase dbuf, split-K=2, bf16 partials over dead WgeT/WueT
  gemm_down_2ph<<<dim3(8, 32, 2), 256, 0, stream>>>(HBUF, WddT, dp01);

  // out = rmsnorm(dense)*w_post1 + rmsnorm(routed)*w_post2
  finalize_kernel<<<4096, 256, 0, stream>>>(dp01, dp01 + (size_t)4096 * 1024, down_e,
                                            pair_pos, w_post1, w_post2, out);
}

// Round 9
// 413.830 us; speedup vs baseline: 1.0761x; 1.0761x over previous
//
#include <hip/hip_runtime.h>
#include <hip/hip_bf16.h>
#include <cstdint>

// ---------------------------------------------------------------------------
// Gemma4 MoE FFN. N=4096 tokens, H=1024, ID=4096, IM=512, E=8, top-2.
// Round 9: 5 dispatches total. prepass_all (cvt + 6 transposes + router),
// moe_route (hist+scan+assign, 1 block), up_merged (dense+expert fused dual
// up-GEMM), down_merged (dense+expert down GEMM), finalize.
// GEMM core: plain 128x128, BK=64, granule-XOR swizzle (conflicts==0 measured),
// global_load_lds width-16, 3 blocks/CU.
// ---------------------------------------------------------------------------

typedef __attribute__((ext_vector_type(8))) short short8;
typedef __attribute__((ext_vector_type(4))) float floatx4;
typedef const void __attribute__((address_space(1)))* gptr_t;
typedef void __attribute__((address_space(3)))* sptr_t;

#define BF16 __hip_bfloat16

// gelu-tanh via sigmoid identity: x * sigma(1.5957691x + 0.07135481x^3)
__device__ __forceinline__ float gelu_sig(float x) {
  float z = x * (1.5957691216f + 0.07135481283f * x * x);
  return x / (1.f + __expf(-z));
}

__device__ __forceinline__ unsigned bf16bits(float f) {
  union { BF16 b; unsigned short u; } c;
  c.b = __float2bfloat16(f);
  return c.u;
}
__device__ __forceinline__ float bits2f(unsigned bf) {
  union { unsigned u; float f; } c;
  c.u = bf << 16;
  return c.f;
}

// ---------------------------------------------------------------------------
// [128][64] bf16 tile staging, granule-XOR swizzle. LDS slot g holds source
// granule g ^ (row&7); frag64 applies the same XOR on read.
// ---------------------------------------------------------------------------
__device__ __forceinline__ void stage128x64(const BF16* __restrict__ g, BF16* lds,
                                            int ldg, int wave, int lane) {
  const int rsub = lane >> 3;
  const int gcol = lane & 7;
#pragma unroll
  for (int j = 0; j < 4; ++j) {
    int row = wave * 32 + j * 8 + rsub;
    const BF16* src = g + (size_t)row * ldg + ((gcol ^ rsub) * 8);
    BF16* dst = lds + (wave * 32 + j * 8) * 64;  // wave-uniform; HW adds lane*16B
    __builtin_amdgcn_global_load_lds((gptr_t)src, (sptr_t)dst, 16, 0, 0);
  }
}

__device__ __forceinline__ void stage128x64_indir(const BF16* __restrict__ xr,
                                                  const int* __restrict__ tok,
                                                  int kofs, BF16* lds, int wave, int lane) {
  const int rsub = lane >> 3;
  const int gcol = lane & 7;
#pragma unroll
  for (int j = 0; j < 4; ++j) {
    const BF16* src = xr + (size_t)tok[j] * 1024 + kofs + ((gcol ^ rsub) * 8);
    BF16* dst = lds + (wave * 32 + j * 8) * 64;
    __builtin_amdgcn_global_load_lds((gptr_t)src, (sptr_t)dst, 16, 0, 0);
  }
}

__device__ __forceinline__ short8 frag64(const BF16* lds, int fr, int kh, int lane) {
  int gk = kh * 4 + (lane >> 4);
  return *(const short8*)&lds[fr * 64 + ((gk ^ (fr & 7)) * 8)];
}

// ---------------------------------------------------------------------------
// Fused dual up-GEMM body (two K-passes over shared LDS; K=1024).
// pass1: G = A@Bg -> pg = bf16(gelu(G)) packed; pass2: U = A@Bu;
// out = pg*U (*row_w). Tile 128x128. All pointers pre-offset to the tile.
// ---------------------------------------------------------------------------
template <int INDIR, int GROUPED>
__device__ __forceinline__ void up_body(const BF16* __restrict__ Abase,
                                        const int* __restrict__ rtok,
                                        const BF16* __restrict__ Bgr,
                                        const BF16* __restrict__ Bur,
                                        const float* __restrict__ rww,
                                        BF16* __restrict__ outt, int ldo,
                                        BF16* la, BF16* lb, int wave, int lane) {
  constexpr int NKT = 16;
  const int wr = wave >> 1, wc = wave & 1;
  int tok[4];
  if (INDIR) {
#pragma unroll
    for (int j = 0; j < 4; ++j) {
      int t = rtok[wave * 32 + j * 8 + (lane >> 3)];
      tok[j] = t < 0 ? 0 : t;
    }
  }

  unsigned pg[4][4][2];
  {
    floatx4 accg[4][4] = {};
    for (int kt = 0; kt < NKT; ++kt) {
      if (INDIR)
        stage128x64_indir(Abase, tok, kt * 64, la, wave, lane);
      else
        stage128x64(Abase + kt * 64, la, 1024, wave, lane);
      stage128x64(Bgr + kt * 64, lb, 1024, wave, lane);
      __syncthreads();
#pragma unroll
      for (int kh = 0; kh < 2; ++kh) {
        short8 af[4], bf[4];
#pragma unroll
        for (int mi = 0; mi < 4; ++mi)
          af[mi] = frag64(la, wr * 64 + mi * 16 + (lane & 15), kh, lane);
#pragma unroll
        for (int ni = 0; ni < 4; ++ni)
          bf[ni] = frag64(lb, wc * 64 + ni * 16 + (lane & 15), kh, lane);
#pragma unroll
        for (int mi = 0; mi < 4; ++mi)
#pragma unroll
          for (int ni = 0; ni < 4; ++ni)
            accg[mi][ni] = __builtin_amdgcn_mfma_f32_16x16x32_bf16(af[mi], bf[ni], accg[mi][ni], 0, 0, 0);
      }
      __syncthreads();
    }
#pragma unroll
    for (int mi = 0; mi < 4; ++mi)
#pragma unroll
      for (int ni = 0; ni < 4; ++ni) {
        pg[mi][ni][0] = bf16bits(gelu_sig(accg[mi][ni][0])) |
                        (bf16bits(gelu_sig(accg[mi][ni][1])) << 16);
        pg[mi][ni][1] = bf16bits(gelu_sig(accg[mi][ni][2])) |
                        (bf16bits(gelu_sig(accg[mi][ni][3])) << 16);
      }
  }

  floatx4 accu[4][4] = {};
  for (int kt = 0; kt < NKT; ++kt) {
    if (INDIR)
      stage128x64_indir(Abase, tok, kt * 64, la, wave, lane);
    else
      stage128x64(Abase + kt * 64, la, 1024, wave, lane);
    stage128x64(Bur + kt * 64, lb, 1024, wave, lane);
    __syncthreads();
#pragma unroll
    for (int kh = 0; kh < 2; ++kh) {
      short8 af[4], bf[4];
#pragma unroll
      for (int mi = 0; mi < 4; ++mi)
        af[mi] = frag64(la, wr * 64 + mi * 16 + (lane & 15), kh, lane);
#pragma unroll
      for (int ni = 0; ni < 4; ++ni)
        bf[ni] = frag64(lb, wc * 64 + ni * 16 + (lane & 15), kh, lane);
#pragma unroll
      for (int mi = 0; mi < 4; ++mi)
#pragma unroll
        for (int ni = 0; ni < 4; ++ni)
          accu[mi][ni] = __builtin_amdgcn_mfma_f32_16x16x32_bf16(af[mi], bf[ni], accu[mi][ni], 0, 0, 0);
    }
    __syncthreads();
  }

  float rw[4][4];
  if (GROUPED) {
#pragma unroll
    for (int mi = 0; mi < 4; ++mi)
#pragma unroll
      for (int j = 0; j < 4; ++j)
        rw[mi][j] = rww[wr * 64 + mi * 16 + (lane >> 4) * 4 + j];
  }
#pragma unroll
  for (int mi = 0; mi < 4; ++mi)
#pragma unroll
    for (int ni = 0; ni < 4; ++ni)
#pragma unroll
      for (int j = 0; j < 4; ++j) {
        int r = wr * 64 + mi * 16 + (lane >> 4) * 4 + j;
        int c = wc * 64 + ni * 16 + (lane & 15);
        float g = bits2f((pg[mi][ni][j >> 1] >> ((j & 1) * 16)) & 0xffffu);
        float v = g * accu[mi][ni][j];
        if (GROUPED) v *= rw[mi][j];
        outt[(size_t)r * ldo + c] = __float2bfloat16(v);
      }
}

// Plain GEMM body (down GEMMs), pointers pre-offset to the tile.
__device__ __forceinline__ void gemm_body(const BF16* __restrict__ Ar, int lda,
                                          const BF16* __restrict__ Br, int ldb,
                                          BF16* __restrict__ outt, int ldo, int nkt,
                                          BF16* la, BF16* lb, int wave, int lane) {
  const int wr = wave >> 1, wc = wave & 1;
  floatx4 acc[4][4] = {};
  for (int kt = 0; kt < nkt; ++kt) {
    stage128x64(Ar + kt * 64, la, lda, wave, lane);
    stage128x64(Br + kt * 64, lb, ldb, wave, lane);
    __syncthreads();
#pragma unroll
    for (int kh = 0; kh < 2; ++kh) {
      short8 af[4], bf[4];
#pragma unroll
      for (int mi = 0; mi < 4; ++mi)
        af[mi] = frag64(la, wr * 64 + mi * 16 + (lane & 15), kh, lane);
#pragma unroll
      for (int ni = 0; ni < 4; ++ni)
        bf[ni] = frag64(lb, wc * 64 + ni * 16 + (lane & 15), kh, lane);
#pragma unroll
      for (int mi = 0; mi < 4; ++mi)
#pragma unroll
        for (int ni = 0; ni < 4; ++ni)
          acc[mi][ni] = __builtin_amdgcn_mfma_f32_16x16x32_bf16(af[mi], bf[ni], acc[mi][ni], 0, 0, 0);
    }
    __syncthreads();
  }
#pragma unroll
  for (int mi = 0; mi < 4; ++mi)
#pragma unroll
    for (int ni = 0; ni < 4; ++ni)
#pragma unroll
      for (int j = 0; j < 4; ++j) {
        int r = wr * 64 + mi * 16 + (lane >> 4) * 4 + j;
        int c = wc * 64 + ni * 16 + (lane & 15);
        outt[(size_t)r * ldo + c] = __float2bfloat16(acc[mi][ni][j]);
      }
}

// ---------------------------------------------------------------------------
// up_merged: bid<1024 dense (32x32 tiles of HBUF=gelu(x@Wg)*(x@Wu));
//            bid>=1024: expert tiles (4 col-blocks x 72 desc) of
//            HBUF_e=gelu(xr@Wge)*(xr@Wue)*row_w with row_token indirection.
// ---------------------------------------------------------------------------
__launch_bounds__(256, 3)
__global__ void up_merged(const BF16* __restrict__ x_b, const BF16* __restrict__ WgdT,
                          const BF16* __restrict__ WudT, const BF16* __restrict__ xr_b,
                          const BF16* __restrict__ WgeT, const BF16* __restrict__ WueT,
                          const int2* __restrict__ desc, const int* __restrict__ row_token,
                          const float* __restrict__ row_w,
                          BF16* __restrict__ HBUF, BF16* __restrict__ HBUF_e) {
  __shared__ __align__(16) BF16 la[128 * 64];
  __shared__ __align__(16) BF16 lb[128 * 64];
  const int bid = blockIdx.x;
  const int lane = threadIdx.x & 63, wave = threadIdx.x >> 6;
  if (bid < 1024) {
    const int r0 = (bid >> 5) * 128, c0 = (bid & 31) * 128;
    up_body<0, 0>(x_b + (size_t)r0 * 1024, nullptr,
                  WgdT + (size_t)c0 * 1024, WudT + (size_t)c0 * 1024, nullptr,
                  HBUF + (size_t)r0 * 4096 + c0, 4096, la, lb, wave, lane);
  } else {
    const int p = bid - 1024;
    int2 d = desc[p >> 2];
    if (d.x < 0) return;
    const int r0 = d.y, c0 = (p & 3) * 128;
    up_body<1, 1>(xr_b, row_token + r0,
                  WgeT + (size_t)(d.x * 512 + c0) * 1024,
                  WueT + (size_t)(d.x * 512 + c0) * 1024, row_w + r0,
                  HBUF_e + (size_t)r0 * 512 + c0, 512, la, lb, wave, lane);
  }
}

// ---------------------------------------------------------------------------
// down_merged: bid<256 dense (dense_pre = HBUF@Wd_d, K=4096);
//              bid>=256 expert (down_e = HBUF_e@Wd_e[e], K=512).
// ---------------------------------------------------------------------------
__launch_bounds__(256, 3)
__global__ void down_merged(const BF16* __restrict__ HBUF, const BF16* __restrict__ WddT,
                            const BF16* __restrict__ HBUF_e,
                            const BF16* __restrict__ WdeT_e,
                            const int2* __restrict__ desc,
                            BF16* __restrict__ dense_pre, BF16* __restrict__ down_e) {
  __shared__ __align__(16) BF16 la[128 * 64];
  __shared__ __align__(16) BF16 lb[128 * 64];
  const int bid = blockIdx.x;
  const int lane = threadIdx.x & 63, wave = threadIdx.x >> 6;
  if (bid < 256) {
    const int r0 = (bid >> 3) * 128, c0 = (bid & 7) * 128;
    gemm_body(HBUF + (size_t)r0 * 4096, 4096, WddT + (size_t)c0 * 4096, 4096,
              dense_pre + (size_t)r0 * 1024 + c0, 1024, 64, la, lb, wave, lane);
  } else {
    const int p = bid - 256;
    int2 d = desc[p >> 3];
    if (d.x < 0) return;
    const int r0 = d.y, c0 = (p & 7) * 128;
    gemm_body(HBUF_e + (size_t)r0 * 512, 512,
              WdeT_e + ((size_t)d.x * 1024 + c0) * 512, 512,
              down_e + (size_t)r0 * 1024 + c0, 1024, 8, la, lb, wave, lane);
  }
}

// ---------------------------------------------------------------------------
// prepass_all: bid<4096: x f32->bf16 cvt. bid in [4096,28672): one of 6
// weight transposes (4096 blocks each, 32x32 f32->bf16 transpose tiles).
// bid>=28672: router (1024 blocks, 4 tokens each).
// ---------------------------------------------------------------------------
__global__ void prepass_all(const float* __restrict__ x, const float* __restrict__ Wg_d,
                            const float* __restrict__ Wu_d, const float* __restrict__ Wd_d,
                            const float* __restrict__ Wg_e, const float* __restrict__ Wu_e,
                            const float* __restrict__ Wd_e,
                            const float* __restrict__ residual,
                            const float* __restrict__ w_pre2,
                            const float* __restrict__ router_scale,
                            const float* __restrict__ per_expert_scale,
                            const float* __restrict__ Wr,
                            BF16* __restrict__ x_b, BF16* __restrict__ WgdT,
                            BF16* __restrict__ WudT, BF16* __restrict__ WddT,
                            BF16* __restrict__ WgeT, BF16* __restrict__ WueT,
                            BF16* __restrict__ WdeT_e, BF16* __restrict__ xr,
                            int* __restrict__ top_i, float* __restrict__ top_w) {
  __shared__ float tile[32][33];
  const int bid = blockIdx.x, tid = threadIdx.x;

  if (bid < 4096) {  // x cvt
    const size_t i = ((size_t)bid * 256 + tid) * 4;
    float4 v = *(const float4*)(x + i);
    BF16 o[4] = {__float2bfloat16(v.x), __float2bfloat16(v.y),
                 __float2bfloat16(v.z), __float2bfloat16(v.w)};
    *(uint2*)(x_b + i) = *(const uint2*)o;
    return;
  }
  if (bid < 28672) {  // transposes: out[b][c][r] = bf16(in[b][r][c])
    const int op = (bid - 4096) >> 12;
    const int rblk = (bid - 4096) & 4095;
    const float* in;
    BF16* outp;
    int rows, cols, bx, by, bz = 0;
    if (op == 0) { in = Wg_d; outp = WgdT; rows = 1024; cols = 4096; bx = rblk & 127; by = rblk >> 7; }
    else if (op == 1) { in = Wu_d; outp = WudT; rows = 1024; cols = 4096; bx = rblk & 127; by = rblk >> 7; }
    else if (op == 2) { in = Wd_d; outp = WddT; rows = 4096; cols = 1024; bx = rblk & 31; by = rblk >> 5; }
    else if (op == 3) { in = Wg_e; outp = WgeT; rows = 1024; cols = 512; bx = rblk & 15; by = (rblk >> 4) & 31; bz = rblk >> 9; }
    else if (op == 4) { in = Wu_e; outp = WueT; rows = 1024; cols = 512; bx = rblk & 15; by = (rblk >> 4) & 31; bz = rblk >> 9; }
    else { in = Wd_e; outp = WdeT_e; rows = 512; cols = 1024; bx = rblk & 31; by = (rblk >> 5) & 15; bz = rblk >> 9; }
    const size_t boff = (size_t)bz * rows * cols;
    in += boff;
    outp += boff;
    const int c0 = bx * 32, r0 = by * 32;
    const int tx = tid & 31, ty = tid >> 5;
#pragma unroll
    for (int i = 0; i < 4; ++i)
      tile[ty + i * 8][tx] = in[(size_t)(r0 + ty + i * 8) * cols + c0 + tx];
    __syncthreads();
#pragma unroll
    for (int i = 0; i < 4; ++i)
      outp[(size_t)(c0 + ty + i * 8) * rows + r0 + tx] =
          __float2bfloat16(tile[tx][ty + i * 8]);
    return;
  }

  // router
  const int lane = tid & 63, wv = tid >> 6;
  const int n = (bid - 28672) * 4 + wv;
  const float* res = residual + (size_t)n * 1024;
  float v[16];
  float ss = 0.f;
#pragma unroll
  for (int i = 0; i < 16; ++i) {
    v[i] = res[lane + i * 64];
    ss += v[i] * v[i];
  }
#pragma unroll
  for (int off = 32; off; off >>= 1) ss += __shfl_xor(ss, off);
  const float inv = rsqrtf(ss * (1.f / 1024.f) + 1e-6f);

  float logits[8] = {};
#pragma unroll
  for (int i = 0; i < 16; ++i) {
    int h = lane + i * 64;
    float nv = v[i] * inv;
    xr[(size_t)n * 1024 + h] = __float2bfloat16(nv * w_pre2[h]);
    float yv = nv * router_scale[h];
#pragma unroll
    for (int ex = 0; ex < 8; ++ex) logits[ex] += yv * Wr[h * 8 + ex];
  }
#pragma unroll
  for (int ex = 0; ex < 8; ++ex)
#pragma unroll
    for (int off = 32; off; off >>= 1) logits[ex] += __shfl_xor(logits[ex], off);

  if (lane == 0) {
    const float hscale = 0.03125f;  // 1024^-0.5
    float mx = -1e30f;
#pragma unroll
    for (int ex = 0; ex < 8; ++ex) {
      logits[ex] *= hscale;
      mx = fmaxf(mx, logits[ex]);
    }
    float p[8];
#pragma unroll
    for (int ex = 0; ex < 8; ++ex) p[ex] = __expf(logits[ex] - mx);
    int i0 = 0;
#pragma unroll
    for (int ex = 1; ex < 8; ++ex)
      if (p[ex] > p[i0]) i0 = ex;
    int i1 = -1;
#pragma unroll
    for (int ex = 0; ex < 8; ++ex)
      if (ex != i0 && (i1 < 0 || p[ex] > p[i1])) i1 = ex;
    float w0 = p[i0], w1 = p[i1];
    float swv = w0 + w1;
    w0 = w0 / swv * per_expert_scale[i0];
    w1 = w1 / swv * per_expert_scale[i1];
    top_i[n * 2] = i0;
    top_i[n * 2 + 1] = i1;
    top_w[n * 2] = w0;
    top_w[n * 2 + 1] = w1;
  }
}

// ---------------------------------------------------------------------------
// moe_route: single block. Chunked LDS histogram -> serial scan (offsets,
// desc, per-chunk bases) -> row init -> chunked rank assign. No global atomics.
// ---------------------------------------------------------------------------
__global__ void moe_route(const int* __restrict__ top_i, const float* __restrict__ top_w,
                          int2* __restrict__ desc, int* __restrict__ row_token,
                          float* __restrict__ row_w, int* __restrict__ pair_pos) {
  __shared__ int ch[32][8];
  __shared__ int cb[32][8];
  const int t = threadIdx.x;
  ch[t >> 3][t & 7] = 0;
  __syncthreads();
  for (int c = 0; c < 32; ++c) atomicAdd(&ch[c][top_i[c * 256 + t]], 1);
  __syncthreads();
  if (t == 0) {
    int acc = 0, td = 0;
    for (int e = 0; e < 8; ++e) {
      int cnt = 0;
      for (int c = 0; c < 32; ++c) cnt += ch[c][e];
      int run = acc;
      for (int c = 0; c < 32; ++c) {
        cb[c][e] = run;
        run += ch[c][e];
      }
      int ntile = (cnt + 127) >> 7;
      for (int k = 0; k < ntile; ++k) desc[td++] = make_int2(e, acc + k * 128);
      acc += ntile * 128;
    }
    for (; td < 72; ++td) desc[td] = make_int2(-1, 0);
  }
  __syncthreads();
  ch[t >> 3][t & 7] = 0;  // reuse as cursors
  for (int i = t; i < 9216; i += 256) {
    row_token[i] = -1;
    row_w[i] = 0.f;
  }
  __syncthreads();
  for (int c = 0; c < 32; ++c) {
    const int p = c * 256 + t;
    const int e = top_i[p];
    const int rank = atomicAdd(&ch[c][e], 1);  // LDS atomic
    const int pos = cb[c][e] + rank;
    row_token[pos] = p >> 1;
    row_w[pos] = top_w[p];
    pair_pos[p] = pos;
  }
}

// ---------------------------------------------------------------------------
// Finalize: routed = down_e[p0]+down_e[p1];
// out = rmsnorm(dense_pre)*w_post1 + rmsnorm(routed)*w_post2
// ---------------------------------------------------------------------------
__global__ void finalize_kernel(const BF16* __restrict__ dp, const BF16* __restrict__ de,
                                const int* __restrict__ pair_pos,
                                const float* __restrict__ w1, const float* __restrict__ w2,
                                float* __restrict__ out) {
  const int n = blockIdx.x, t = threadIdx.x;
  const int p0 = pair_pos[n * 2], p1 = pair_pos[n * 2 + 1];
  float d[4], r[4];
  float ssd = 0.f, ssr = 0.f;
#pragma unroll
  for (int i = 0; i < 4; ++i) {
    int h = t + i * 256;
    d[i] = __bfloat162float(dp[(size_t)n * 1024 + h]);
    r[i] = __bfloat162float(de[(size_t)p0 * 1024 + h]) +
           __bfloat162float(de[(size_t)p1 * 1024 + h]);
    ssd += d[i] * d[i];
    ssr += r[i] * r[i];
  }
#pragma unroll
  for (int off = 32; off; off >>= 1) {
    ssd += __shfl_xor(ssd, off);
    ssr += __shfl_xor(ssr, off);
  }
  __shared__ float sd[4], sr[4];
  int wave = t >> 6, lane = t & 63;
  if (lane == 0) {
    sd[wave] = ssd;
    sr[wave] = ssr;
  }
  __syncthreads();
  ssd = sd[0] + sd[1] + sd[2] + sd[3];
  ssr = sr[0] + sr[1] + sr[2] + sr[3];
  const float invd = rsqrtf(ssd * (1.f / 1024.f) + 1e-6f);
  const float invr = rsqrtf(ssr * (1.f / 1024.f) + 1e-6f);
#pragma unroll
  for (int i = 0; i < 4; ++i) {
    int h = t + i * 256;
    out[(size_t)n * 1024 + h] = d[i] * invd * w1[h] + r[i] * invr * w2[h];
  }
}

// ---------------------------------------------------------------------------
// Workspace (MiB offsets; lifetime-checked):
//   0..8   x_b    [P -> up]
//   8..16  xr_b   [P -> up]
//  16..24  WgdT   [P -> up];   dense_pre [down -> fin] (WgdT dead after up)
//  24..32  WudT   [P -> up]
//  32..40  WddT   [P -> down]
//  40..48  WgeT   [P -> up]
//  48..56  WueT   [P -> up]
//  56..64  WdeT_e [P -> down]
//  64..96  HBUF   [up -> down]
//  96..105 HBUF_e [up -> down]
// 106..124 down_e [down -> fin]
// 124..124.2 S bookkeeping [P(router) -> fin]
// ---------------------------------------------------------------------------
extern "C" void kernel_launch(void* const* d_in, const int* in_sizes, int n_in,
                              void* d_out, int out_size, void* d_ws, size_t ws_size,
                              hipStream_t stream) {
  const float* x = (const float*)d_in[0];
  const float* res = (const float*)d_in[1];
  const float* Wg_d = (const float*)d_in[2];
  const float* Wu_d = (const float*)d_in[3];
  const float* Wd_d = (const float*)d_in[4];
  const float* w_post1 = (const float*)d_in[5];
  const float* w_pre2 = (const float*)d_in[6];
  const float* w_post2 = (const float*)d_in[7];
  const float* router_scale = (const float*)d_in[8];
  const float* per_expert_scale = (const float*)d_in[9];
  const float* Wr = (const float*)d_in[10];
  const float* Wg_e = (const float*)d_in[11];
  const float* Wu_e = (const float*)d_in[12];
  const float* Wd_e = (const float*)d_in[13];
  float* out = (float*)d_out;

  char* ws = (char*)d_ws;
  const size_t MB = 1ull << 20;
  BF16* x_b = (BF16*)(ws + 0 * MB);
  BF16* xr_b = (BF16*)(ws + 8 * MB);
  BF16* WgdT = (BF16*)(ws + 16 * MB);
  BF16* dense_pre = (BF16*)(ws + 16 * MB);  // aliases WgdT (dead after up)
  BF16* WudT = (BF16*)(ws + 24 * MB);
  BF16* WddT = (BF16*)(ws + 32 * MB);
  BF16* WgeT = (BF16*)(ws + 40 * MB);
  BF16* WueT = (BF16*)(ws + 48 * MB);
  BF16* WdeT_e = (BF16*)(ws + 56 * MB);
  BF16* HBUF = (BF16*)(ws + 64 * MB);
  BF16* HBUF_e = (BF16*)(ws + 96 * MB);
  BF16* down_e = (BF16*)(ws + 106 * MB);
  char* S = ws + 124 * MB;
  int* top_i = (int*)(S);                   // [8192]
  float* top_w = (float*)(S + 32 * 1024);   // [8192]
  int* pair_pos = (int*)(S + 64 * 1024);    // [8192]
  int* row_token = (int*)(S + 96 * 1024);   // [9216]
  float* row_w = (float*)(S + 136 * 1024);  // [9216]
  int2* desc = (int2*)(S + 176 * 1024);     // [72]

  // 1. prepass: cvt + 6 transposes + router (29696 blocks)
  prepass_all<<<29696, 256, 0, stream>>>(x, Wg_d, Wu_d, Wd_d, Wg_e, Wu_e, Wd_e,
                                         res, w_pre2, router_scale, per_expert_scale,
                                         Wr, x_b, WgdT, WudT, WddT, WgeT, WueT,
                                         WdeT_e, xr_b, top_i, top_w);
  // 2. routing bookkeeping (1 block)
  moe_route<<<1, 256, 0, stream>>>(top_i, top_w, desc, row_token, row_w, pair_pos);
  // 3. up GEMMs (dense 1024 + expert 288 blocks)
  up_merged<<<1312, 256, 0, stream>>>(x_b, WgdT, WudT, xr_b, WgeT, WueT, desc,
                                      row_token, row_w, HBUF, HBUF_e);
  // 4. down GEMMs (dense 256 + expert 576 blocks)
  down_merged<<<832, 256, 0, stream>>>(HBUF, WddT, HBUF_e, WdeT_e, desc, dense_pre,
                                       down_e);
  // 5. finalize
  finalize_kernel<<<4096, 256, 0, stream>>>(dense_pre, down_e, pair_pos, w_post1,
                                            w_post2, out);
}